// Round 17
// baseline (217.773 us; speedup 1.0000x reference)
//
#include <hip/hip_runtime.h>

typedef __bf16 bf16x8 __attribute__((ext_vector_type(8)));
typedef short short8 __attribute__((ext_vector_type(8)));
typedef float f32x4 __attribute__((ext_vector_type(4)));
typedef float f32x2 __attribute__((ext_vector_type(2)));
typedef unsigned short ushort_t;

// ---------- helpers ----------
__device__ __forceinline__ ushort_t f2bf(float f) {
  union { float f; unsigned u; } v; v.f = f;
  unsigned r = v.u + 0x7fffu + ((v.u >> 16) & 1u);   // RNE
  return (ushort_t)(r >> 16);
}
__device__ __forceinline__ float bf2f(ushort_t u) {
  return __int_as_float(((unsigned)u) << 16);
}

__device__ __forceinline__ void g2lds16(const void* g, void* l) {
  __builtin_amdgcn_global_load_lds(
      (const __attribute__((address_space(1))) void*)g,
      (__attribute__((address_space(3))) void*)l, 16, 0, 0);
}

__device__ __forceinline__ float fexp2(float x) {
#if __has_builtin(__builtin_amdgcn_exp2f)
  return __builtin_amdgcn_exp2f(x);
#else
  return exp2f(x);
#endif
}

// VALU-pipe exp2: rndne + sub + 3 fma + cvt + v_ldexp (7 full-rate ops).
// Arg range here is [-5.4, 0]; deg-3 Taylor on f in [-0.5,0.5]: rel err <= 6e-4.
__device__ __forceinline__ float fexp2p(float x) {
  float n = rintf(x);
  float f = x - n;
  float r = fmaf(f, 0.05550411f, 0.24022651f);
  r = fmaf(r, f, 0.69314718f);
  r = fmaf(r, f, 1.0f);
  return ldexpf(r, (int)n);
}

__device__ __forceinline__ f32x2 pk_fma(f32x2 a, f32x2 b, f32x2 c) {
#if __has_builtin(__builtin_elementwise_fma)
  return __builtin_elementwise_fma(a, b, c);
#else
  return (f32x2){fmaf(a.x, b.x, c.x), fmaf(a.y, b.y, c.y)};
#endif
}

template<int CTRL>
__device__ __forceinline__ float dpp_step(float x) {
  int t = __builtin_amdgcn_update_dpp(0, __float_as_int(x), CTRL, 0xf, 0xf, false);
  return x + __int_as_float(t);
}
// full 64-lane sum; result valid on lane 63
__device__ __forceinline__ float wave_sum64(float v) {
  v = dpp_step<0x111>(v);
  v = dpp_step<0x112>(v);
  v = dpp_step<0x114>(v);
  v = dpp_step<0x118>(v);
  v = dpp_step<0x142>(v);
  v = dpp_step<0x143>(v);
  return v;
}
// 16-lane row sum; result valid on lane 15 of each row16
__device__ __forceinline__ float row_sum16(float v) {
  v = dpp_step<0x111>(v);
  v = dpp_step<0x112>(v);
  v = dpp_step<0x114>(v);
  v = dpp_step<0x118>(v);
  return v;
}

// ---------- fused prep: x->bf16 conversion + 3 weight transposes ----------
__global__ __launch_bounds__(256)
void prep_kernel(const float* __restrict__ x, ushort_t* __restrict__ xbf,
                 const float* __restrict__ W_in, ushort_t* __restrict__ WinT,
                 const float* __restrict__ W_x, ushort_t* __restrict__ WxT,
                 const float* __restrict__ W_out, ushort_t* __restrict__ WoutT) {
  __shared__ float tile[32][33];
  const int r = blockIdx.x, tid = threadIdx.x;
  if (r < 1536) {                      // conv f32->bf16, 2048x768
    int i = (r * 256 + tid) * 4;
    float4 v = *(const float4*)(x + i);
    union { ushort_t u[4]; uint2 v2; } o;
    o.u[0] = f2bf(v.x); o.u[1] = f2bf(v.y); o.u[2] = f2bf(v.z); o.u[3] = f2bf(v.w);
    *(uint2*)(xbf + i) = o.v2;
    return;
  }
  const float* W; ushort_t* Wt; int K, N, bx, by;
  if (r < 3840)      { int rr = r - 1536; W = W_in;  Wt = WinT;  K = 768;  N = 3072; bx = rr % 96; by = rr / 96; }
  else if (r < 6336) { int rr = r - 3840; W = W_x;   Wt = WxT;   K = 1536; N = 1664; bx = rr % 52; by = rr / 52; }
  else               { int rr = r - 6336; W = W_out; Wt = WoutT; K = 1536; N = 768;  bx = rr % 24; by = rr / 24; }
  const int n0 = bx * 32, k0 = by * 32;
  const int tx = tid & 31, ty = tid >> 5;
#pragma unroll
  for (int rr = 0; rr < 32; rr += 8)
    tile[ty + rr][tx] = W[(size_t)(k0 + ty + rr) * N + n0 + tx];
  __syncthreads();
#pragma unroll
  for (int rr = 0; rr < 32; rr += 8)
    Wt[(size_t)(n0 + ty + rr) * K + k0 + tx] = f2bf(tile[tx][ty + rr]);
}

// ---------- bf16 MFMA GEMM: 64x64 tile, BK=32, 4 waves (2x2, wave = 32x32) ----
// MODE 0: n<1536 -> xs_bf (out1); else sres_bf (out2) — both silu, bf16 only
// MODE 1: out0=v (ldc 1664)
// MODE 2: split-K 2 partial: blockIdx.z = K-chunk; out0 = partial (ldc 768)
template<int MODE>
__global__ __launch_bounds__(256)
void gemm64(const ushort_t* __restrict__ A, const ushort_t* __restrict__ Bt,
            const int K, const int lda, const int ldb,
            float* __restrict__ out0, ushort_t* __restrict__ out1,
            ushort_t* __restrict__ out2) {
  __shared__ __align__(16) ushort_t Asl[64 * 32];
  __shared__ __align__(16) ushort_t Bsl[64 * 32];
  const int tid = threadIdx.x;
  const int lane = tid & 63;
  const int wid = tid >> 6;
  const int wm = wid >> 1, wn = wid & 1;
  const int lr = lane & 15, lk = lane >> 4;
  const int bm = blockIdx.y, bn = blockIdx.x;
  const ushort_t* Ab;
  const ushort_t* Bb;
  float* o0 = out0;
  if (MODE == 2) {
    const int z = blockIdx.z;
    Ab = A + z * 768 + (size_t)bm * 64 * lda;
    Bb = Bt + z * 768 + (size_t)bn * 64 * ldb;
    o0 = out0 + (size_t)z * 2048 * 768;
  } else {
    Ab = A + (size_t)bm * 64 * lda;
    Bb = Bt + (size_t)bn * 64 * ldb;
  }

  f32x4 acc[2][2];
#pragma unroll
  for (int i = 0; i < 2; ++i)
#pragma unroll
    for (int j = 0; j < 2; ++j) acc[i][j] = (f32x4){0.f, 0.f, 0.f, 0.f};

  for (int k0 = 0; k0 < K; k0 += 32) {
    const int cb = wid << 6;
    const int ch = cb + lane;
    const int row = ch >> 2;
    const int c8 = (ch & 3) << 3;
    g2lds16(Ab + (size_t)row * lda + k0 + c8, Asl + (size_t)cb * 8);
    g2lds16(Bb + (size_t)row * ldb + k0 + c8, Bsl + (size_t)cb * 8);
    __syncthreads();
    short8 av[2], bv[2];
#pragma unroll
    for (int i = 0; i < 2; ++i)
      av[i] = *(const short8*)(Asl + ((wm * 32 + i * 16 + lr) * 32 + lk * 8));
#pragma unroll
    for (int j = 0; j < 2; ++j)
      bv[j] = *(const short8*)(Bsl + ((wn * 32 + j * 16 + lr) * 32 + lk * 8));
#pragma unroll
    for (int i = 0; i < 2; ++i)
#pragma unroll
      for (int j = 0; j < 2; ++j)
        acc[i][j] = __builtin_amdgcn_mfma_f32_16x16x32_bf16(
            __builtin_bit_cast(bf16x8, av[i]), __builtin_bit_cast(bf16x8, bv[j]),
            acc[i][j], 0, 0, 0);
    __syncthreads();
  }

  const int mb = bm * 64 + wm * 32 + (lane >> 4) * 4;
  const int nb = bn * 64 + wn * 32 + lr;
#pragma unroll
  for (int i = 0; i < 2; ++i) {
#pragma unroll
    for (int j = 0; j < 2; ++j) {
      const int n = nb + j * 16;
#pragma unroll
      for (int r = 0; r < 4; ++r) {
        const int m = mb + i * 16 + r;
        float v = acc[i][j][r];
        if (MODE == 0) {
          float sv = v / (1.f + __expf(-v));   // silu
          if (n < 1536) out1[(size_t)m * 1536 + n] = f2bf(sv);
          else          out2[(size_t)m * 1536 + (n - 1536)] = f2bf(sv);
        } else if (MODE == 1) {
          out0[(size_t)m * 1664 + n] = v;
        } else {
          o0[(size_t)m * 768 + n] = v;   // raw partial
        }
      }
    }
  }
}

// ---------- time-segmented selective scan with FUSED delta-GEMM ----------
// Grid = dim3(16, 96, 2): seg fastest. xs/sres consumed as bf16.
// Pipe-balanced exponentials: even step -> v_exp_f32 (trans pipe), odd step ->
// polynomial exp2 (VALU pipe) so both pipes carry ~half the decay-exp load.

__global__ __launch_bounds__(256)
void scan_pass1(const float* __restrict__ xdbl, const ushort_t* __restrict__ xs,
                const float* __restrict__ W_dt, const float* __restrict__ b_dt,
                const float* __restrict__ A_log,
                float* __restrict__ Qb, float* __restrict__ Dsum) {
  __shared__ __align__(16) char region[16384];
  __shared__ float dsp[8][16];
  ushort_t* Btl = (ushort_t*)region;                 // [0,8192)  persistent
  f32x4* ddl = (f32x4*)(region + 8192);              // [8192,16384) persistent
  ushort_t* DinF = (ushort_t*)region;                // [0,8704)  transient
  ushort_t* WdtS = (ushort_t*)(region + 8704);       // [8704,10880) transient
  const int tid = threadIdx.x;
  const int lane = tid & 63;
  const int wid = tid >> 6;
  const int i16 = lane & 15;
  const int lk = lane >> 4;
  const int ch = wid * 4 + lk;
  const int seg = blockIdx.x, b = blockIdx.z;
  const int d0 = blockIdx.y * 16;
  const int d = d0 + ch;
  const int t0 = seg << 6;
  const size_t r0 = (size_t)b * 1024;

  // transient stage: delta_in tile [t][k] bf16 + W_dt slice [ch][k] bf16
#pragma unroll
  for (int i = 0; i < 4; ++i) {
    int q = i * 256 + tid;
    int t = q >> 4, k4 = (q & 15) << 2;
    float4 v = *(const float4*)(xdbl + (r0 + t0 + t) * 1664 + 64 + k4);
    union { ushort_t u[4]; uint2 p; } o;
    o.u[0] = f2bf(v.x); o.u[1] = f2bf(v.y); o.u[2] = f2bf(v.z); o.u[3] = f2bf(v.w);
    *(uint2*)&DinF[t * 68 + k4] = o.p;
  }
  {
    int k = tid >> 2, c4 = (tid & 3) << 2;
    float4 w = *(const float4*)(W_dt + (size_t)k * 1536 + d0 + c4);
    WdtS[(c4 + 0) * 68 + k] = f2bf(w.x);
    WdtS[(c4 + 1) * 68 + k] = f2bf(w.y);
    WdtS[(c4 + 2) * 68 + k] = f2bf(w.z);
    WdtS[(c4 + 3) * 68 + k] = f2bf(w.w);
  }
  const float bbias = b_dt[d0 + i16];
  float4 Av = *(const float4*)(A_log + (size_t)d * 64 + i16 * 4);
  const f32x2 A01 = {-__expf(Av.x) * 1.44269504f, -__expf(Av.y) * 1.44269504f};
  const f32x2 A23 = {-__expf(Av.z) * 1.44269504f, -__expf(Av.w) * 1.44269504f};
  __syncthreads();

  // delta GEMM: 2 MFMAs; wave wid covers t rows wid*16..+15
  f32x4 dacc = (f32x4){0.f, 0.f, 0.f, 0.f};
  {
    short8 a0 = *(const short8*)&DinF[(wid * 16 + i16) * 68 + lk * 8];
    short8 b0 = *(const short8*)&WdtS[i16 * 68 + lk * 8];
    dacc = __builtin_amdgcn_mfma_f32_16x16x32_bf16(
        __builtin_bit_cast(bf16x8, a0), __builtin_bit_cast(bf16x8, b0), dacc, 0, 0, 0);
    short8 a1 = *(const short8*)&DinF[(wid * 16 + i16) * 68 + 32 + lk * 8];
    short8 b1 = *(const short8*)&WdtS[i16 * 68 + 32 + lk * 8];
    dacc = __builtin_amdgcn_mfma_f32_16x16x32_bf16(
        __builtin_bit_cast(bf16x8, a1), __builtin_bit_cast(bf16x8, b1), dacc, 0, 0, 0);
  }
  float sp[4], dx[4];
  const int tbase = wid * 16 + lk * 4;
#pragma unroll
  for (int r = 0; r < 4; ++r) {
    float a = dacc[r] + bbias;
    float s = fmaxf(a, 0.f) + log1pf(__expf(-fabsf(a)));
    sp[r] = fminf(s, 10.f);
    dx[r] = sp[r] * bf2f(xs[(r0 + t0 + tbase + r) * 1536 + d0 + i16]);
  }
  float part = (sp[0] + sp[1]) + (sp[2] + sp[3]);
  part += __int_as_float(__builtin_amdgcn_ds_swizzle(__float_as_int(part), 0x401F));
  __syncthreads();   // all DinF/WdtS reads done
  if ((lane & 16) == 0) dsp[wid * 2 + (lane >> 5)][i16] = part;
  {
    const int t2a = tbase >> 1;
    ddl[t2a * 16 + (i16 ^ (t2a & 15))] = (f32x4){sp[0], dx[0], sp[1], dx[1]};
    const int t2b = t2a + 1;
    ddl[t2b * 16 + (i16 ^ (t2b & 15))] = (f32x4){sp[2], dx[2], sp[3], dx[3]};
  }
#pragma unroll
  for (int i = 0; i < 2; ++i) {
    int q = i * 256 + tid;
    int t2 = q >> 4, s0 = (q & 15) << 2;
    const float* rowE = xdbl + (r0 + t0 + 2 * t2) * 1664 + s0;
    float4 ve = *(const float4*)rowE;
    float4 vo = *(const float4*)(rowE + 1664);
    uint4 u;
    u.x = f2bf(ve.x) | ((unsigned)f2bf(vo.x) << 16);
    u.y = f2bf(ve.y) | ((unsigned)f2bf(vo.y) << 16);
    u.z = f2bf(ve.z) | ((unsigned)f2bf(vo.z) << 16);
    u.w = f2bf(ve.w) | ((unsigned)f2bf(vo.w) << 16);
    *(uint4*)&Btl[(t2 * 64 + s0) * 2] = u;
  }
  __syncthreads();
  if (tid < 16) {
    float s = ((dsp[0][tid] + dsp[1][tid]) + (dsp[2][tid] + dsp[3][tid])) +
              ((dsp[4][tid] + dsp[5][tid]) + (dsp[6][tid] + dsp[7][tid]));
    Dsum[(size_t)(b * 16 + seg) * 1536 + d0 + tid] = s;
  }

  const char* ddb = (const char*)ddl;
  const char* Bb8 = (const char*)Btl + (i16 << 4);
  const int chb = ch << 4;
  f32x2 h01 = {0.f, 0.f}, h23 = {0.f, 0.f};
#pragma unroll
  for (int t2 = 0; t2 < 32; ++t2) {
    f32x4 dd = *(const f32x4*)(ddb + t2 * 256 + (chb ^ ((t2 & 15) << 4)));
    uint4 ub = *(const uint4*)(Bb8 + t2 * 256);
    f32x2 b01 = {__int_as_float(ub.x << 16), __int_as_float(ub.y << 16)};
    f32x2 b23 = {__int_as_float(ub.z << 16), __int_as_float(ub.w << 16)};
    f32x2 dt2 = {dd.x, dd.x}, dx2 = {dd.y, dd.y};
    f32x2 m01 = dt2 * A01, m23 = dt2 * A23;
    h01 = pk_fma((f32x2){fexp2(m01.x), fexp2(m01.y)}, h01, dx2 * b01);
    h23 = pk_fma((f32x2){fexp2(m23.x), fexp2(m23.y)}, h23, dx2 * b23);
    b01 = (f32x2){__int_as_float(ub.x & 0xFFFF0000u), __int_as_float(ub.y & 0xFFFF0000u)};
    b23 = (f32x2){__int_as_float(ub.z & 0xFFFF0000u), __int_as_float(ub.w & 0xFFFF0000u)};
    dt2 = (f32x2){dd.z, dd.z}; dx2 = (f32x2){dd.w, dd.w};
    m01 = dt2 * A01; m23 = dt2 * A23;
    h01 = pk_fma((f32x2){fexp2p(m01.x), fexp2p(m01.y)}, h01, dx2 * b01);
    h23 = pk_fma((f32x2){fexp2p(m23.x), fexp2p(m23.y)}, h23, dx2 * b23);
  }
  const size_t sbq = (size_t)(b * 16 + seg) * 1536 + d;
  *(float4*)(Qb + sbq * 64 + i16 * 4) = make_float4(h01.x, h01.y, h23.x, h23.y);
}

__global__ __launch_bounds__(256)
void scan_combine(float* __restrict__ Qb, const float* __restrict__ Dsum,
                  const float* __restrict__ A_log) {
  const int tid = threadIdx.x;
  const int lane = tid & 63;
  const int wave = blockIdx.x * 4 + (tid >> 6);
  const int bb = (wave >= 1536) ? 1 : 0;
  const int d = wave - bb * 1536;
  const float Aval2 = -__expf(A_log[(size_t)d * 64 + lane]) * 1.44269504f;
  float qv[16], Pv[16];
#pragma unroll
  for (int j = 0; j < 16; ++j) {
    const size_t sb = ((size_t)(bb * 16 + j) * 1536 + d);
    qv[j] = Qb[sb * 64 + lane];
    Pv[j] = fexp2(Aval2 * Dsum[sb]);
  }
  float h = 0.f;
#pragma unroll
  for (int j = 0; j < 16; ++j) {
    const size_t sb = ((size_t)(bb * 16 + j) * 1536 + d);
    Qb[sb * 64 + lane] = h;
    h = fmaf(Pv[j], h, qv[j]);
  }
}

__global__ __launch_bounds__(256)
void scan_pass2(const float* __restrict__ xdbl, const ushort_t* __restrict__ xs,
                const ushort_t* __restrict__ sres, const float* __restrict__ W_dt,
                const float* __restrict__ b_dt, const float* __restrict__ A_log,
                const float* __restrict__ Dp, const float* __restrict__ Qb,
                ushort_t* __restrict__ ybf) {
  __shared__ __align__(16) char region[16384];
  __shared__ __align__(16) f32x2 ytl[32 * 16];
  ushort_t* Btl = (ushort_t*)region;
  f32x4* ddl = (f32x4*)(region + 8192);
  ushort_t* DinF = (ushort_t*)region;
  ushort_t* WdtS = (ushort_t*)(region + 8704);
  const int tid = threadIdx.x;
  const int lane = tid & 63;
  const int wid = tid >> 6;
  const int i16 = lane & 15;
  const int lk = lane >> 4;
  const int ch = wid * 4 + lk;
  const int seg = blockIdx.x, b = blockIdx.z;
  const int d0 = blockIdx.y * 16;
  const int d = d0 + ch;
  const int t0 = seg << 6;
  const size_t r0 = (size_t)b * 1024;

#pragma unroll
  for (int i = 0; i < 4; ++i) {
    int q = i * 256 + tid;
    int t = q >> 4, k4 = (q & 15) << 2;
    float4 v = *(const float4*)(xdbl + (r0 + t0 + t) * 1664 + 64 + k4);
    union { ushort_t u[4]; uint2 p; } o;
    o.u[0] = f2bf(v.x); o.u[1] = f2bf(v.y); o.u[2] = f2bf(v.z); o.u[3] = f2bf(v.w);
    *(uint2*)&DinF[t * 68 + k4] = o.p;
  }
  {
    int k = tid >> 2, c4 = (tid & 3) << 2;
    float4 w = *(const float4*)(W_dt + (size_t)k * 1536 + d0 + c4);
    WdtS[(c4 + 0) * 68 + k] = f2bf(w.x);
    WdtS[(c4 + 1) * 68 + k] = f2bf(w.y);
    WdtS[(c4 + 2) * 68 + k] = f2bf(w.z);
    WdtS[(c4 + 3) * 68 + k] = f2bf(w.w);
  }
  const float bbias = b_dt[d0 + i16];
  float4 Av = *(const float4*)(A_log + (size_t)d * 64 + i16 * 4);
  const f32x2 A01 = {-__expf(Av.x) * 1.44269504f, -__expf(Av.y) * 1.44269504f};
  const f32x2 A23 = {-__expf(Av.z) * 1.44269504f, -__expf(Av.w) * 1.44269504f};
  const size_t sbq = (size_t)(b * 16 + seg) * 1536 + d;
  float4 hq = *(const float4*)(Qb + sbq * 64 + i16 * 4);
  f32x2 h01 = {hq.x, hq.y}, h23 = {hq.z, hq.w};
  __syncthreads();

  f32x4 dacc = (f32x4){0.f, 0.f, 0.f, 0.f};
  {
    short8 a0 = *(const short8*)&DinF[(wid * 16 + i16) * 68 + lk * 8];
    short8 b0 = *(const short8*)&WdtS[i16 * 68 + lk * 8];
    dacc = __builtin_amdgcn_mfma_f32_16x16x32_bf16(
        __builtin_bit_cast(bf16x8, a0), __builtin_bit_cast(bf16x8, b0), dacc, 0, 0, 0);
    short8 a1 = *(const short8*)&DinF[(wid * 16 + i16) * 68 + 32 + lk * 8];
    short8 b1 = *(const short8*)&WdtS[i16 * 68 + 32 + lk * 8];
    dacc = __builtin_amdgcn_mfma_f32_16x16x32_bf16(
        __builtin_bit_cast(bf16x8, a1), __builtin_bit_cast(bf16x8, b1), dacc, 0, 0, 0);
  }
  float sp[4], dx[4];
  const int tbase = wid * 16 + lk * 4;
#pragma unroll
  for (int r = 0; r < 4; ++r) {
    float a = dacc[r] + bbias;
    float s = fmaxf(a, 0.f) + log1pf(__expf(-fabsf(a)));
    sp[r] = fminf(s, 10.f);
    dx[r] = sp[r] * bf2f(xs[(r0 + t0 + tbase + r) * 1536 + d0 + i16]);
  }
  __syncthreads();
  {
    const int t2a = tbase >> 1;
    ddl[t2a * 16 + (i16 ^ (t2a & 15))] = (f32x4){sp[0], dx[0], sp[1], dx[1]};
    const int t2b = t2a + 1;
    ddl[t2b * 16 + (i16 ^ (t2b & 15))] = (f32x4){sp[2], dx[2], sp[3], dx[3]};
  }
#pragma unroll
  for (int i = 0; i < 2; ++i) {
    int q = i * 256 + tid;
    int t2 = q >> 4, s0 = (q & 15) << 2;
    const float* rowE = xdbl + (r0 + t0 + 2 * t2) * 1664 + s0;
    float4 ve = *(const float4*)rowE;
    float4 vo = *(const float4*)(rowE + 1664);
    uint4 u;
    u.x = f2bf(ve.x) | ((unsigned)f2bf(vo.x) << 16);
    u.y = f2bf(ve.y) | ((unsigned)f2bf(vo.y) << 16);
    u.z = f2bf(ve.z) | ((unsigned)f2bf(vo.z) << 16);
    u.w = f2bf(ve.w) | ((unsigned)f2bf(vo.w) << 16);
    *(uint4*)&Btl[(t2 * 64 + s0) * 2] = u;
  }
  __syncthreads();

  const char* ddb = (const char*)ddl;
  const char* Bb8 = (const char*)Btl + (i16 << 4);
  const int chb = ch << 4;
  const bool wlane = (i16 == 15);
#pragma unroll
  for (int t2 = 0; t2 < 32; ++t2) {
    f32x4 dd = *(const f32x4*)(ddb + t2 * 256 + (chb ^ ((t2 & 15) << 4)));
    uint4 ub = *(const uint4*)(Bb8 + t2 * 256);
    f32x2 b01 = {__int_as_float(ub.x << 16), __int_as_float(ub.y << 16)};
    f32x2 b23 = {__int_as_float(ub.z << 16), __int_as_float(ub.w << 16)};
    f32x2 dt2 = {dd.x, dd.x}, dx2 = {dd.y, dd.y};
    f32x2 m01 = dt2 * A01, m23 = dt2 * A23;
    h01 = pk_fma((f32x2){fexp2(m01.x), fexp2(m01.y)}, h01, dx2 * b01);
    h23 = pk_fma((f32x2){fexp2(m23.x), fexp2(m23.y)}, h23, dx2 * b23);
    f32x2 hsE = h01 + h23;
    float WE = row_sum16(hsE.x + hsE.y);
    b01 = (f32x2){__int_as_float(ub.x & 0xFFFF0000u), __int_as_float(ub.y & 0xFFFF0000u)};
    b23 = (f32x2){__int_as_float(ub.z & 0xFFFF0000u), __int_as_float(ub.w & 0xFFFF0000u)};
    dt2 = (f32x2){dd.z, dd.z}; dx2 = (f32x2){dd.w, dd.w};
    m01 = dt2 * A01; m23 = dt2 * A23;
    h01 = pk_fma((f32x2){fexp2p(m01.x), fexp2p(m01.y)}, h01, dx2 * b01);
    h23 = pk_fma((f32x2){fexp2p(m23.x), fexp2p(m23.y)}, h23, dx2 * b23);
    f32x2 hsO = h01 + h23;
    float WO = row_sum16(hsO.x + hsO.y);
    if (wlane) ytl[t2 * 16 + ch] = (f32x2){WE, WO};
  }
  __syncthreads();

  const int ch2 = tid & 15;
  const int tr = tid >> 4;
  const float dp2 = Dp[d0 + ch2];
  const float* ytf = (const float*)ytl;
#pragma unroll
  for (int r2 = 0; r2 < 4; ++r2) {
    const int t = tr + (r2 << 4);
    const size_t gi = r0 + t0 + t;
    float yv = ytf[(t >> 1) * 32 + ch2 * 2 + (t & 1)];
    float Ct = xdbl[gi * 1664 + 128 + d0 + ch2];
    float xt = bf2f(xs[gi * 1536 + d0 + ch2]);
    float rt = bf2f(sres[gi * 1536 + d0 + ch2]);
    ybf[gi * 1536 + d0 + ch2] = f2bf((Ct * yv + xt * dp2) * rt);
  }
}

// ---------- LayerNorm (row = 768) over sum of 2 split-K partials + residual ----------
__global__ __launch_bounds__(256)
void ln_kernel(const float* __restrict__ part, const float* __restrict__ x,
               const float* __restrict__ g, const float* __restrict__ be,
               float* __restrict__ outp) {
  const int row = blockIdx.x, tid = threadIdx.x;
  const size_t ro = (size_t)row * 768;
  const float* p0 = part + ro;
  const float* p1 = part + 1572864 + ro;
  const float* xr = x + ro;
  float v0 = p0[tid] + p1[tid] + xr[tid];
  float v1 = p0[tid + 256] + p1[tid + 256] + xr[tid + 256];
  float v2 = p0[tid + 512] + p1[tid + 512] + xr[tid + 512];
  __shared__ float sb[4];
  const int wid = tid >> 6;
  float s = wave_sum64(v0 + v1 + v2);
  if ((tid & 63) == 63) sb[wid] = s;
  __syncthreads();
  float mu = (sb[0] + sb[1] + sb[2] + sb[3]) * (1.f / 768.f);
  __syncthreads();
  float d0 = v0 - mu, d1 = v1 - mu, d2 = v2 - mu;
  float q = wave_sum64(d0 * d0 + d1 * d1 + d2 * d2);
  if ((tid & 63) == 63) sb[wid] = q;
  __syncthreads();
  float var = (sb[0] + sb[1] + sb[2] + sb[3]) * (1.f / 768.f);
  float inv = rsqrtf(var + 1e-5f);
  float* po = outp + ro;
  po[tid]       = d0 * inv * g[tid]       + be[tid];
  po[tid + 256] = d1 * inv * g[tid + 256] + be[tid + 256];
  po[tid + 512] = d2 * inv * g[tid + 512] + be[tid + 512];
}

// ---------- launch ----------
extern "C" void kernel_launch(void* const* d_in, const int* in_sizes, int n_in,
                              void* d_out, int out_size, void* d_ws, size_t ws_size,
                              hipStream_t stream) {
  (void)in_sizes; (void)n_in; (void)out_size; (void)ws_size;
  const float* x     = (const float*)d_in[0];
  const float* W_in  = (const float*)d_in[1];
  const float* W_x   = (const float*)d_in[2];
  const float* W_dt  = (const float*)d_in[3];
  const float* b_dt  = (const float*)d_in[4];
  const float* A_log = (const float*)d_in[5];
  const float* Dp    = (const float*)d_in[6];
  const float* W_out = (const float*)d_in[7];
  const float* ln_g  = (const float*)d_in[8];
  const float* ln_b  = (const float*)d_in[9];
  float* out = (float*)d_out;
  char* ws = (char*)d_ws;

  ushort_t* xbf   = (ushort_t*)(ws + 0);          // [dead after gemm0]
  ushort_t* WinT  = (ushort_t*)(ws + 3145728);    // [dead after gemm0]
  ushort_t* WxT   = (ushort_t*)(ws + 7864320);    // [dead after gemm1]
  ushort_t* WoutT = (ushort_t*)(ws + 12976128);
  ushort_t* xs_bf = (ushort_t*)(ws + 27918336);   // 2048x1536 bf16
  ushort_t* sres_bf = (ushort_t*)(ws + 34209792); // 2048x1536 bf16
  float*    xdbl  = (float*)   (ws + 46792704);   // 2048x1664 f32
  ushort_t* ybf   = (ushort_t*)(ws + 73007104);   // 2048x1536 bf16
  float*    Qbuf  = (float*)   (ws + 0);          // reuses dead xbf/WinT
  float*    Dsum  = (float*)   (ws + 12582912);
  float*    part  = (float*)   (ws + 15335424);   // reuses free region

  prep_kernel<<<7488, 256, 0, stream>>>(x, xbf, W_in, WinT, W_x, WxT, W_out, WoutT);

  gemm64<0><<<dim3(48, 32), 256, 0, stream>>>(xbf, WinT, 768, 768, 768,
                                              nullptr, xs_bf, sres_bf);
  gemm64<1><<<dim3(26, 32), 256, 0, stream>>>(xs_bf, WxT, 1536, 1536, 1536,
                                              xdbl, nullptr, nullptr);

  scan_pass1<<<dim3(16, 96, 2), 256, 0, stream>>>(xdbl, xs_bf, W_dt, b_dt, A_log,
                                                  Qbuf, Dsum);
  scan_combine<<<768, 256, 0, stream>>>(Qbuf, Dsum, A_log);
  scan_pass2<<<dim3(16, 96, 2), 256, 0, stream>>>(xdbl, xs_bf, sres_bf, W_dt, b_dt,
                                                  A_log, Dp, Qbuf, ybf);

  gemm64<2><<<dim3(12, 32, 2), 256, 0, stream>>>(ybf, WoutT, 768, 1536, 1536,
                                                 part, nullptr, nullptr);
  ln_kernel<<<2048, 256, 0, stream>>>(part, x, ln_g, ln_b, out);
}

// Round 18
// 194.514 us; speedup vs baseline: 1.1196x; 1.1196x over previous
//
#include <hip/hip_runtime.h>

typedef __bf16 bf16x8 __attribute__((ext_vector_type(8)));
typedef short short8 __attribute__((ext_vector_type(8)));
typedef float f32x4 __attribute__((ext_vector_type(4)));
typedef float f32x2 __attribute__((ext_vector_type(2)));
typedef unsigned short ushort_t;

// ---------- helpers ----------
__device__ __forceinline__ ushort_t f2bf(float f) {
  union { float f; unsigned u; } v; v.f = f;
  unsigned r = v.u + 0x7fffu + ((v.u >> 16) & 1u);   // RNE
  return (ushort_t)(r >> 16);
}
__device__ __forceinline__ float bf2f(ushort_t u) {
  return __int_as_float(((unsigned)u) << 16);
}

__device__ __forceinline__ void g2lds16(const void* g, void* l) {
  __builtin_amdgcn_global_load_lds(
      (const __attribute__((address_space(1))) void*)g,
      (__attribute__((address_space(3))) void*)l, 16, 0, 0);
}

__device__ __forceinline__ float fexp2(float x) {
#if __has_builtin(__builtin_amdgcn_exp2f)
  return __builtin_amdgcn_exp2f(x);
#else
  return exp2f(x);
#endif
}

__device__ __forceinline__ f32x2 pk_fma(f32x2 a, f32x2 b, f32x2 c) {
#if __has_builtin(__builtin_elementwise_fma)
  return __builtin_elementwise_fma(a, b, c);
#else
  return (f32x2){fmaf(a.x, b.x, c.x), fmaf(a.y, b.y, c.y)};
#endif
}

template<int CTRL>
__device__ __forceinline__ float dpp_step(float x) {
  int t = __builtin_amdgcn_update_dpp(0, __float_as_int(x), CTRL, 0xf, 0xf, false);
  return x + __int_as_float(t);
}
// full 64-lane sum; result valid on lane 63
__device__ __forceinline__ float wave_sum64(float v) {
  v = dpp_step<0x111>(v);
  v = dpp_step<0x112>(v);
  v = dpp_step<0x114>(v);
  v = dpp_step<0x118>(v);
  v = dpp_step<0x142>(v);
  v = dpp_step<0x143>(v);
  return v;
}
// 16-lane row sum; result valid on lane 15 of each row16
__device__ __forceinline__ float row_sum16(float v) {
  v = dpp_step<0x111>(v);
  v = dpp_step<0x112>(v);
  v = dpp_step<0x114>(v);
  v = dpp_step<0x118>(v);
  return v;
}

// ---------- fused prep: x->bf16 conversion + 3 weight transposes ----------
__global__ __launch_bounds__(256)
void prep_kernel(const float* __restrict__ x, ushort_t* __restrict__ xbf,
                 const float* __restrict__ W_in, ushort_t* __restrict__ WinT,
                 const float* __restrict__ W_x, ushort_t* __restrict__ WxT,
                 const float* __restrict__ W_out, ushort_t* __restrict__ WoutT) {
  __shared__ float tile[32][33];
  const int r = blockIdx.x, tid = threadIdx.x;
  if (r < 1536) {                      // conv f32->bf16, 2048x768
    int i = (r * 256 + tid) * 4;
    float4 v = *(const float4*)(x + i);
    union { ushort_t u[4]; uint2 v2; } o;
    o.u[0] = f2bf(v.x); o.u[1] = f2bf(v.y); o.u[2] = f2bf(v.z); o.u[3] = f2bf(v.w);
    *(uint2*)(xbf + i) = o.v2;
    return;
  }
  const float* W; ushort_t* Wt; int K, N, bx, by;
  if (r < 3840)      { int rr = r - 1536; W = W_in;  Wt = WinT;  K = 768;  N = 3072; bx = rr % 96; by = rr / 96; }
  else if (r < 6336) { int rr = r - 3840; W = W_x;   Wt = WxT;   K = 1536; N = 1664; bx = rr % 52; by = rr / 52; }
  else               { int rr = r - 6336; W = W_out; Wt = WoutT; K = 1536; N = 768;  bx = rr % 24; by = rr / 24; }
  const int n0 = bx * 32, k0 = by * 32;
  const int tx = tid & 31, ty = tid >> 5;
#pragma unroll
  for (int rr = 0; rr < 32; rr += 8)
    tile[ty + rr][tx] = W[(size_t)(k0 + ty + rr) * N + n0 + tx];
  __syncthreads();
#pragma unroll
  for (int rr = 0; rr < 32; rr += 8)
    Wt[(size_t)(n0 + ty + rr) * K + k0 + tx] = f2bf(tile[tx][ty + rr]);
}

// ---------- bf16 MFMA GEMM: 64x64 tile, BK=32, 4 waves (2x2, wave = 32x32) ----
// MODE 0: n<1536 -> xs_bf (out1); else sres_bf (out2) — both silu, bf16 only
// MODE 1: out0=v (ldc 1664)
// MODE 2: split-K 2 partial: blockIdx.z = K-chunk; out0 = partial (ldc 768)
template<int MODE>
__global__ __launch_bounds__(256)
void gemm64(const ushort_t* __restrict__ A, const ushort_t* __restrict__ Bt,
            const int K, const int lda, const int ldb,
            float* __restrict__ out0, ushort_t* __restrict__ out1,
            ushort_t* __restrict__ out2) {
  __shared__ __align__(16) ushort_t Asl[64 * 32];
  __shared__ __align__(16) ushort_t Bsl[64 * 32];
  const int tid = threadIdx.x;
  const int lane = tid & 63;
  const int wid = tid >> 6;
  const int wm = wid >> 1, wn = wid & 1;
  const int lr = lane & 15, lk = lane >> 4;
  const int bm = blockIdx.y, bn = blockIdx.x;
  const ushort_t* Ab;
  const ushort_t* Bb;
  float* o0 = out0;
  if (MODE == 2) {
    const int z = blockIdx.z;
    Ab = A + z * 768 + (size_t)bm * 64 * lda;
    Bb = Bt + z * 768 + (size_t)bn * 64 * ldb;
    o0 = out0 + (size_t)z * 2048 * 768;
  } else {
    Ab = A + (size_t)bm * 64 * lda;
    Bb = Bt + (size_t)bn * 64 * ldb;
  }

  f32x4 acc[2][2];
#pragma unroll
  for (int i = 0; i < 2; ++i)
#pragma unroll
    for (int j = 0; j < 2; ++j) acc[i][j] = (f32x4){0.f, 0.f, 0.f, 0.f};

  for (int k0 = 0; k0 < K; k0 += 32) {
    const int cb = wid << 6;
    const int ch = cb + lane;
    const int row = ch >> 2;
    const int c8 = (ch & 3) << 3;
    g2lds16(Ab + (size_t)row * lda + k0 + c8, Asl + (size_t)cb * 8);
    g2lds16(Bb + (size_t)row * ldb + k0 + c8, Bsl + (size_t)cb * 8);
    __syncthreads();
    short8 av[2], bv[2];
#pragma unroll
    for (int i = 0; i < 2; ++i)
      av[i] = *(const short8*)(Asl + ((wm * 32 + i * 16 + lr) * 32 + lk * 8));
#pragma unroll
    for (int j = 0; j < 2; ++j)
      bv[j] = *(const short8*)(Bsl + ((wn * 32 + j * 16 + lr) * 32 + lk * 8));
#pragma unroll
    for (int i = 0; i < 2; ++i)
#pragma unroll
      for (int j = 0; j < 2; ++j)
        acc[i][j] = __builtin_amdgcn_mfma_f32_16x16x32_bf16(
            __builtin_bit_cast(bf16x8, av[i]), __builtin_bit_cast(bf16x8, bv[j]),
            acc[i][j], 0, 0, 0);
    __syncthreads();
  }

  const int mb = bm * 64 + wm * 32 + (lane >> 4) * 4;
  const int nb = bn * 64 + wn * 32 + lr;
#pragma unroll
  for (int i = 0; i < 2; ++i) {
#pragma unroll
    for (int j = 0; j < 2; ++j) {
      const int n = nb + j * 16;
#pragma unroll
      for (int r = 0; r < 4; ++r) {
        const int m = mb + i * 16 + r;
        float v = acc[i][j][r];
        if (MODE == 0) {
          float sv = v / (1.f + __expf(-v));   // silu
          if (n < 1536) out1[(size_t)m * 1536 + n] = f2bf(sv);
          else          out2[(size_t)m * 1536 + (n - 1536)] = f2bf(sv);
        } else if (MODE == 1) {
          out0[(size_t)m * 1664 + n] = v;
        } else {
          o0[(size_t)m * 768 + n] = v;   // raw partial
        }
      }
    }
  }
}

// ---------- time-segmented selective scan with FUSED delta-GEMM ----------
// Grid = dim3(16, 96, 2): seg fastest (d0-fastest duplicates the per-seg
// B-tile across all 8 XCD L2s: FETCH 30->53MB, +14us — measured R15).
// xs/sres consumed as bf16. All decay exps on the trans pipe (v_exp_f32);
// R17's VALU-poly split regressed 82->103us (kernel is VALU-issue-bound).

__global__ __launch_bounds__(256)
void scan_pass1(const float* __restrict__ xdbl, const ushort_t* __restrict__ xs,
                const float* __restrict__ W_dt, const float* __restrict__ b_dt,
                const float* __restrict__ A_log,
                float* __restrict__ Qb, float* __restrict__ Dsum) {
  __shared__ __align__(16) char region[16384];
  __shared__ float dsp[8][16];
  ushort_t* Btl = (ushort_t*)region;                 // [0,8192)  persistent
  f32x4* ddl = (f32x4*)(region + 8192);              // [8192,16384) persistent
  ushort_t* DinF = (ushort_t*)region;                // [0,8704)  transient
  ushort_t* WdtS = (ushort_t*)(region + 8704);       // [8704,10880) transient
  const int tid = threadIdx.x;
  const int lane = tid & 63;
  const int wid = tid >> 6;
  const int i16 = lane & 15;
  const int lk = lane >> 4;
  const int ch = wid * 4 + lk;
  const int seg = blockIdx.x, b = blockIdx.z;
  const int d0 = blockIdx.y * 16;
  const int d = d0 + ch;
  const int t0 = seg << 6;
  const size_t r0 = (size_t)b * 1024;

  // transient stage: delta_in tile [t][k] bf16 + W_dt slice [ch][k] bf16
#pragma unroll
  for (int i = 0; i < 4; ++i) {
    int q = i * 256 + tid;
    int t = q >> 4, k4 = (q & 15) << 2;
    float4 v = *(const float4*)(xdbl + (r0 + t0 + t) * 1664 + 64 + k4);
    union { ushort_t u[4]; uint2 p; } o;
    o.u[0] = f2bf(v.x); o.u[1] = f2bf(v.y); o.u[2] = f2bf(v.z); o.u[3] = f2bf(v.w);
    *(uint2*)&DinF[t * 68 + k4] = o.p;
  }
  {
    int k = tid >> 2, c4 = (tid & 3) << 2;
    float4 w = *(const float4*)(W_dt + (size_t)k * 1536 + d0 + c4);
    WdtS[(c4 + 0) * 68 + k] = f2bf(w.x);
    WdtS[(c4 + 1) * 68 + k] = f2bf(w.y);
    WdtS[(c4 + 2) * 68 + k] = f2bf(w.z);
    WdtS[(c4 + 3) * 68 + k] = f2bf(w.w);
  }
  const float bbias = b_dt[d0 + i16];
  float4 Av = *(const float4*)(A_log + (size_t)d * 64 + i16 * 4);
  const f32x2 A01 = {-__expf(Av.x) * 1.44269504f, -__expf(Av.y) * 1.44269504f};
  const f32x2 A23 = {-__expf(Av.z) * 1.44269504f, -__expf(Av.w) * 1.44269504f};
  __syncthreads();

  // delta GEMM: 2 MFMAs; wave wid covers t rows wid*16..+15
  f32x4 dacc = (f32x4){0.f, 0.f, 0.f, 0.f};
  {
    short8 a0 = *(const short8*)&DinF[(wid * 16 + i16) * 68 + lk * 8];
    short8 b0 = *(const short8*)&WdtS[i16 * 68 + lk * 8];
    dacc = __builtin_amdgcn_mfma_f32_16x16x32_bf16(
        __builtin_bit_cast(bf16x8, a0), __builtin_bit_cast(bf16x8, b0), dacc, 0, 0, 0);
    short8 a1 = *(const short8*)&DinF[(wid * 16 + i16) * 68 + 32 + lk * 8];
    short8 b1 = *(const short8*)&WdtS[i16 * 68 + 32 + lk * 8];
    dacc = __builtin_amdgcn_mfma_f32_16x16x32_bf16(
        __builtin_bit_cast(bf16x8, a1), __builtin_bit_cast(bf16x8, b1), dacc, 0, 0, 0);
  }
  float sp[4], dx[4];
  const int tbase = wid * 16 + lk * 4;
#pragma unroll
  for (int r = 0; r < 4; ++r) {
    float a = dacc[r] + bbias;
    float s = fmaxf(a, 0.f) + log1pf(__expf(-fabsf(a)));
    sp[r] = fminf(s, 10.f);
    dx[r] = sp[r] * bf2f(xs[(r0 + t0 + tbase + r) * 1536 + d0 + i16]);
  }
  float part = (sp[0] + sp[1]) + (sp[2] + sp[3]);
  part += __int_as_float(__builtin_amdgcn_ds_swizzle(__float_as_int(part), 0x401F));
  __syncthreads();   // all DinF/WdtS reads done
  if ((lane & 16) == 0) dsp[wid * 2 + (lane >> 5)][i16] = part;
  {
    const int t2a = tbase >> 1;
    ddl[t2a * 16 + (i16 ^ (t2a & 15))] = (f32x4){sp[0], dx[0], sp[1], dx[1]};
    const int t2b = t2a + 1;
    ddl[t2b * 16 + (i16 ^ (t2b & 15))] = (f32x4){sp[2], dx[2], sp[3], dx[3]};
  }
#pragma unroll
  for (int i = 0; i < 2; ++i) {
    int q = i * 256 + tid;
    int t2 = q >> 4, s0 = (q & 15) << 2;
    const float* rowE = xdbl + (r0 + t0 + 2 * t2) * 1664 + s0;
    float4 ve = *(const float4*)rowE;
    float4 vo = *(const float4*)(rowE + 1664);
    uint4 u;
    u.x = f2bf(ve.x) | ((unsigned)f2bf(vo.x) << 16);
    u.y = f2bf(ve.y) | ((unsigned)f2bf(vo.y) << 16);
    u.z = f2bf(ve.z) | ((unsigned)f2bf(vo.z) << 16);
    u.w = f2bf(ve.w) | ((unsigned)f2bf(vo.w) << 16);
    *(uint4*)&Btl[(t2 * 64 + s0) * 2] = u;
  }
  __syncthreads();
  if (tid < 16) {
    float s = ((dsp[0][tid] + dsp[1][tid]) + (dsp[2][tid] + dsp[3][tid])) +
              ((dsp[4][tid] + dsp[5][tid]) + (dsp[6][tid] + dsp[7][tid]));
    Dsum[(size_t)(b * 16 + seg) * 1536 + d0 + tid] = s;
  }

  const char* ddb = (const char*)ddl;
  const char* Bb8 = (const char*)Btl + (i16 << 4);
  const int chb = ch << 4;
  f32x2 h01 = {0.f, 0.f}, h23 = {0.f, 0.f};
#pragma unroll
  for (int t2 = 0; t2 < 32; ++t2) {
    f32x4 dd = *(const f32x4*)(ddb + t2 * 256 + (chb ^ ((t2 & 15) << 4)));
    uint4 ub = *(const uint4*)(Bb8 + t2 * 256);
    f32x2 b01 = {__int_as_float(ub.x << 16), __int_as_float(ub.y << 16)};
    f32x2 b23 = {__int_as_float(ub.z << 16), __int_as_float(ub.w << 16)};
    f32x2 dt2 = {dd.x, dd.x}, dx2 = {dd.y, dd.y};
    f32x2 m01 = dt2 * A01, m23 = dt2 * A23;
    h01 = pk_fma((f32x2){fexp2(m01.x), fexp2(m01.y)}, h01, dx2 * b01);
    h23 = pk_fma((f32x2){fexp2(m23.x), fexp2(m23.y)}, h23, dx2 * b23);
    b01 = (f32x2){__int_as_float(ub.x & 0xFFFF0000u), __int_as_float(ub.y & 0xFFFF0000u)};
    b23 = (f32x2){__int_as_float(ub.z & 0xFFFF0000u), __int_as_float(ub.w & 0xFFFF0000u)};
    dt2 = (f32x2){dd.z, dd.z}; dx2 = (f32x2){dd.w, dd.w};
    m01 = dt2 * A01; m23 = dt2 * A23;
    h01 = pk_fma((f32x2){fexp2(m01.x), fexp2(m01.y)}, h01, dx2 * b01);
    h23 = pk_fma((f32x2){fexp2(m23.x), fexp2(m23.y)}, h23, dx2 * b23);
  }
  const size_t sbq = (size_t)(b * 16 + seg) * 1536 + d;
  *(float4*)(Qb + sbq * 64 + i16 * 4) = make_float4(h01.x, h01.y, h23.x, h23.y);
}

__global__ __launch_bounds__(256)
void scan_combine(float* __restrict__ Qb, const float* __restrict__ Dsum,
                  const float* __restrict__ A_log) {
  const int tid = threadIdx.x;
  const int lane = tid & 63;
  const int wave = blockIdx.x * 4 + (tid >> 6);
  const int bb = (wave >= 1536) ? 1 : 0;
  const int d = wave - bb * 1536;
  const float Aval2 = -__expf(A_log[(size_t)d * 64 + lane]) * 1.44269504f;
  float qv[16], Pv[16];
#pragma unroll
  for (int j = 0; j < 16; ++j) {
    const size_t sb = ((size_t)(bb * 16 + j) * 1536 + d);
    qv[j] = Qb[sb * 64 + lane];
    Pv[j] = fexp2(Aval2 * Dsum[sb]);
  }
  float h = 0.f;
#pragma unroll
  for (int j = 0; j < 16; ++j) {
    const size_t sb = ((size_t)(bb * 16 + j) * 1536 + d);
    Qb[sb * 64 + lane] = h;
    h = fmaf(Pv[j], h, qv[j]);
  }
}

__global__ __launch_bounds__(256)
void scan_pass2(const float* __restrict__ xdbl, const ushort_t* __restrict__ xs,
                const ushort_t* __restrict__ sres, const float* __restrict__ W_dt,
                const float* __restrict__ b_dt, const float* __restrict__ A_log,
                const float* __restrict__ Dp, const float* __restrict__ Qb,
                ushort_t* __restrict__ ybf) {
  __shared__ __align__(16) char region[16384];
  __shared__ __align__(16) f32x2 ytl[32 * 16];
  ushort_t* Btl = (ushort_t*)region;
  f32x4* ddl = (f32x4*)(region + 8192);
  ushort_t* DinF = (ushort_t*)region;
  ushort_t* WdtS = (ushort_t*)(region + 8704);
  const int tid = threadIdx.x;
  const int lane = tid & 63;
  const int wid = tid >> 6;
  const int i16 = lane & 15;
  const int lk = lane >> 4;
  const int ch = wid * 4 + lk;
  const int seg = blockIdx.x, b = blockIdx.z;
  const int d0 = blockIdx.y * 16;
  const int d = d0 + ch;
  const int t0 = seg << 6;
  const size_t r0 = (size_t)b * 1024;

#pragma unroll
  for (int i = 0; i < 4; ++i) {
    int q = i * 256 + tid;
    int t = q >> 4, k4 = (q & 15) << 2;
    float4 v = *(const float4*)(xdbl + (r0 + t0 + t) * 1664 + 64 + k4);
    union { ushort_t u[4]; uint2 p; } o;
    o.u[0] = f2bf(v.x); o.u[1] = f2bf(v.y); o.u[2] = f2bf(v.z); o.u[3] = f2bf(v.w);
    *(uint2*)&DinF[t * 68 + k4] = o.p;
  }
  {
    int k = tid >> 2, c4 = (tid & 3) << 2;
    float4 w = *(const float4*)(W_dt + (size_t)k * 1536 + d0 + c4);
    WdtS[(c4 + 0) * 68 + k] = f2bf(w.x);
    WdtS[(c4 + 1) * 68 + k] = f2bf(w.y);
    WdtS[(c4 + 2) * 68 + k] = f2bf(w.z);
    WdtS[(c4 + 3) * 68 + k] = f2bf(w.w);
  }
  const float bbias = b_dt[d0 + i16];
  float4 Av = *(const float4*)(A_log + (size_t)d * 64 + i16 * 4);
  const f32x2 A01 = {-__expf(Av.x) * 1.44269504f, -__expf(Av.y) * 1.44269504f};
  const f32x2 A23 = {-__expf(Av.z) * 1.44269504f, -__expf(Av.w) * 1.44269504f};
  const size_t sbq = (size_t)(b * 16 + seg) * 1536 + d;
  float4 hq = *(const float4*)(Qb + sbq * 64 + i16 * 4);
  f32x2 h01 = {hq.x, hq.y}, h23 = {hq.z, hq.w};
  __syncthreads();

  f32x4 dacc = (f32x4){0.f, 0.f, 0.f, 0.f};
  {
    short8 a0 = *(const short8*)&DinF[(wid * 16 + i16) * 68 + lk * 8];
    short8 b0 = *(const short8*)&WdtS[i16 * 68 + lk * 8];
    dacc = __builtin_amdgcn_mfma_f32_16x16x32_bf16(
        __builtin_bit_cast(bf16x8, a0), __builtin_bit_cast(bf16x8, b0), dacc, 0, 0, 0);
    short8 a1 = *(const short8*)&DinF[(wid * 16 + i16) * 68 + 32 + lk * 8];
    short8 b1 = *(const short8*)&WdtS[i16 * 68 + 32 + lk * 8];
    dacc = __builtin_amdgcn_mfma_f32_16x16x32_bf16(
        __builtin_bit_cast(bf16x8, a1), __builtin_bit_cast(bf16x8, b1), dacc, 0, 0, 0);
  }
  float sp[4], dx[4];
  const int tbase = wid * 16 + lk * 4;
#pragma unroll
  for (int r = 0; r < 4; ++r) {
    float a = dacc[r] + bbias;
    float s = fmaxf(a, 0.f) + log1pf(__expf(-fabsf(a)));
    sp[r] = fminf(s, 10.f);
    dx[r] = sp[r] * bf2f(xs[(r0 + t0 + tbase + r) * 1536 + d0 + i16]);
  }
  __syncthreads();
  {
    const int t2a = tbase >> 1;
    ddl[t2a * 16 + (i16 ^ (t2a & 15))] = (f32x4){sp[0], dx[0], sp[1], dx[1]};
    const int t2b = t2a + 1;
    ddl[t2b * 16 + (i16 ^ (t2b & 15))] = (f32x4){sp[2], dx[2], sp[3], dx[3]};
  }
#pragma unroll
  for (int i = 0; i < 2; ++i) {
    int q = i * 256 + tid;
    int t2 = q >> 4, s0 = (q & 15) << 2;
    const float* rowE = xdbl + (r0 + t0 + 2 * t2) * 1664 + s0;
    float4 ve = *(const float4*)rowE;
    float4 vo = *(const float4*)(rowE + 1664);
    uint4 u;
    u.x = f2bf(ve.x) | ((unsigned)f2bf(vo.x) << 16);
    u.y = f2bf(ve.y) | ((unsigned)f2bf(vo.y) << 16);
    u.z = f2bf(ve.z) | ((unsigned)f2bf(vo.z) << 16);
    u.w = f2bf(ve.w) | ((unsigned)f2bf(vo.w) << 16);
    *(uint4*)&Btl[(t2 * 64 + s0) * 2] = u;
  }
  __syncthreads();

  const char* ddb = (const char*)ddl;
  const char* Bb8 = (const char*)Btl + (i16 << 4);
  const int chb = ch << 4;
  const bool wlane = (i16 == 15);
#pragma unroll
  for (int t2 = 0; t2 < 32; ++t2) {
    f32x4 dd = *(const f32x4*)(ddb + t2 * 256 + (chb ^ ((t2 & 15) << 4)));
    uint4 ub = *(const uint4*)(Bb8 + t2 * 256);
    f32x2 b01 = {__int_as_float(ub.x << 16), __int_as_float(ub.y << 16)};
    f32x2 b23 = {__int_as_float(ub.z << 16), __int_as_float(ub.w << 16)};
    f32x2 dt2 = {dd.x, dd.x}, dx2 = {dd.y, dd.y};
    f32x2 m01 = dt2 * A01, m23 = dt2 * A23;
    h01 = pk_fma((f32x2){fexp2(m01.x), fexp2(m01.y)}, h01, dx2 * b01);
    h23 = pk_fma((f32x2){fexp2(m23.x), fexp2(m23.y)}, h23, dx2 * b23);
    f32x2 hsE = h01 + h23;
    float WE = row_sum16(hsE.x + hsE.y);
    b01 = (f32x2){__int_as_float(ub.x & 0xFFFF0000u), __int_as_float(ub.y & 0xFFFF0000u)};
    b23 = (f32x2){__int_as_float(ub.z & 0xFFFF0000u), __int_as_float(ub.w & 0xFFFF0000u)};
    dt2 = (f32x2){dd.z, dd.z}; dx2 = (f32x2){dd.w, dd.w};
    m01 = dt2 * A01; m23 = dt2 * A23;
    h01 = pk_fma((f32x2){fexp2(m01.x), fexp2(m01.y)}, h01, dx2 * b01);
    h23 = pk_fma((f32x2){fexp2(m23.x), fexp2(m23.y)}, h23, dx2 * b23);
    f32x2 hsO = h01 + h23;
    float WO = row_sum16(hsO.x + hsO.y);
    if (wlane) ytl[t2 * 16 + ch] = (f32x2){WE, WO};
  }
  __syncthreads();

  const int ch2 = tid & 15;
  const int tr = tid >> 4;
  const float dp2 = Dp[d0 + ch2];
  const float* ytf = (const float*)ytl;
#pragma unroll
  for (int r2 = 0; r2 < 4; ++r2) {
    const int t = tr + (r2 << 4);
    const size_t gi = r0 + t0 + t;
    float yv = ytf[(t >> 1) * 32 + ch2 * 2 + (t & 1)];
    float Ct = xdbl[gi * 1664 + 128 + d0 + ch2];
    float xt = bf2f(xs[gi * 1536 + d0 + ch2]);
    float rt = bf2f(sres[gi * 1536 + d0 + ch2]);
    ybf[gi * 1536 + d0 + ch2] = f2bf((Ct * yv + xt * dp2) * rt);
  }
}

// ---------- LayerNorm (row = 768) over sum of 2 split-K partials + residual ----------
__global__ __launch_bounds__(256)
void ln_kernel(const float* __restrict__ part, const float* __restrict__ x,
               const float* __restrict__ g, const float* __restrict__ be,
               float* __restrict__ outp) {
  const int row = blockIdx.x, tid = threadIdx.x;
  const size_t ro = (size_t)row * 768;
  const float* p0 = part + ro;
  const float* p1 = part + 1572864 + ro;
  const float* xr = x + ro;
  float v0 = p0[tid] + p1[tid] + xr[tid];
  float v1 = p0[tid + 256] + p1[tid + 256] + xr[tid + 256];
  float v2 = p0[tid + 512] + p1[tid + 512] + xr[tid + 512];
  __shared__ float sb[4];
  const int wid = tid >> 6;
  float s = wave_sum64(v0 + v1 + v2);
  if ((tid & 63) == 63) sb[wid] = s;
  __syncthreads();
  float mu = (sb[0] + sb[1] + sb[2] + sb[3]) * (1.f / 768.f);
  __syncthreads();
  float d0 = v0 - mu, d1 = v1 - mu, d2 = v2 - mu;
  float q = wave_sum64(d0 * d0 + d1 * d1 + d2 * d2);
  if ((tid & 63) == 63) sb[wid] = q;
  __syncthreads();
  float var = (sb[0] + sb[1] + sb[2] + sb[3]) * (1.f / 768.f);
  float inv = rsqrtf(var + 1e-5f);
  float* po = outp + ro;
  po[tid]       = d0 * inv * g[tid]       + be[tid];
  po[tid + 256] = d1 * inv * g[tid + 256] + be[tid + 256];
  po[tid + 512] = d2 * inv * g[tid + 512] + be[tid + 512];
}

// ---------- launch ----------
extern "C" void kernel_launch(void* const* d_in, const int* in_sizes, int n_in,
                              void* d_out, int out_size, void* d_ws, size_t ws_size,
                              hipStream_t stream) {
  (void)in_sizes; (void)n_in; (void)out_size; (void)ws_size;
  const float* x     = (const float*)d_in[0];
  const float* W_in  = (const float*)d_in[1];
  const float* W_x   = (const float*)d_in[2];
  const float* W_dt  = (const float*)d_in[3];
  const float* b_dt  = (const float*)d_in[4];
  const float* A_log = (const float*)d_in[5];
  const float* Dp    = (const float*)d_in[6];
  const float* W_out = (const float*)d_in[7];
  const float* ln_g  = (const float*)d_in[8];
  const float* ln_b  = (const float*)d_in[9];
  float* out = (float*)d_out;
  char* ws = (char*)d_ws;

  ushort_t* xbf   = (ushort_t*)(ws + 0);          // [dead after gemm0]
  ushort_t* WinT  = (ushort_t*)(ws + 3145728);    // [dead after gemm0]
  ushort_t* WxT   = (ushort_t*)(ws + 7864320);    // [dead after gemm1]
  ushort_t* WoutT = (ushort_t*)(ws + 12976128);
  ushort_t* xs_bf = (ushort_t*)(ws + 27918336);   // 2048x1536 bf16
  ushort_t* sres_bf = (ushort_t*)(ws + 34209792); // 2048x1536 bf16
  float*    xdbl  = (float*)   (ws + 46792704);   // 2048x1664 f32
  ushort_t* ybf   = (ushort_t*)(ws + 73007104);   // 2048x1536 bf16
  float*    Qbuf  = (float*)   (ws + 0);          // reuses dead xbf/WinT
  float*    Dsum  = (float*)   (ws + 12582912);
  float*    part  = (float*)   (ws + 15335424);   // reuses free region

  prep_kernel<<<7488, 256, 0, stream>>>(x, xbf, W_in, WinT, W_x, WxT, W_out, WoutT);

  gemm64<0><<<dim3(48, 32), 256, 0, stream>>>(xbf, WinT, 768, 768, 768,
                                              nullptr, xs_bf, sres_bf);
  gemm64<1><<<dim3(26, 32), 256, 0, stream>>>(xs_bf, WxT, 1536, 1536, 1536,
                                              xdbl, nullptr, nullptr);

  scan_pass1<<<dim3(16, 96, 2), 256, 0, stream>>>(xdbl, xs_bf, W_dt, b_dt, A_log,
                                                  Qbuf, Dsum);
  scan_combine<<<768, 256, 0, stream>>>(Qbuf, Dsum, A_log);
  scan_pass2<<<dim3(16, 96, 2), 256, 0, stream>>>(xdbl, xs_bf, sres_bf, W_dt, b_dt,
                                                  A_log, Dp, Qbuf, ybf);

  gemm64<2><<<dim3(12, 32, 2), 256, 0, stream>>>(ybf, WoutT, 768, 1536, 1536,
                                                 part, nullptr, nullptr);
  ln_kernel<<<2048, 256, 0, stream>>>(part, x, ln_g, ln_b, out);
}